// Round 2
// baseline (389.799 us; speedup 1.0000x reference)
//
#include <hip/hip_runtime.h>

#define B_  32
#define T_  256
#define F_  64
#define C_  16
#define CO_ 16
#define P_  64
#define S_  32
#define K_  4
#define FC_ 1024   // F*C
#define OUTC 96
#define TT  8      // t-tile per block
#define NS  14     // TT + 6 halo slices (dilation*(K-1) = 6)

// One fused kernel: block = (b, 8-wide t tile, ALL f).
//  - stage x[t0-6 .. t0+7, :, :] in LDS once (57.3 KB)
//  - phase 1: point GEMM, waves own k-slices (Wp read once/block, L2-hot)
//  - phase 1b: LDS reduce + bias + static term
//  - phase 2: conv with per-(f,co) weights in registers (cw read once/block),
//             fused concat+ReLU stores (64B segments conv/x, 256B point bcast)
__global__ __launch_bounds__(512, 4) void tpc_fused(
    const float* __restrict__ x, const float* __restrict__ stat,
    const float* __restrict__ cw, const float* __restrict__ cb,
    const float* __restrict__ Wp, const float* __restrict__ bp,
    float* __restrict__ out)
{
    __shared__ __align__(16) float xs[NS * FC_];        // 57.3 KB
    __shared__ __align__(16) float part[8 * TT * P_];   // 16 KB
    __shared__ __align__(16) float pout[TT * P_];       // 2 KB  -> 74 KB total

    int tid = threadIdx.x;
    int blk = blockIdx.x;      // 0..1023
    int b  = blk >> 5;
    int t0 = (blk & 31) * TT;

    // ---- stage x[t0-6 .. t0+TT-1, :, :] into LDS (zero left pad) ----
    #pragma unroll
    for (int it = 0; it < 7; ++it) {
        int v = it * 512 + tid;            // float4 id, NS*256 = 3584 total
        int slice = v >> 8;                // 256 float4 per 4KB slice
        int pos   = v & 255;
        int tg = t0 - 6 + slice;
        float4 val = make_float4(0.f, 0.f, 0.f, 0.f);
        if (tg >= 0)
            val = *(const float4*)(x + ((size_t)(b * T_ + tg)) * FC_ + pos * 4);
        *(float4*)(xs + slice * FC_ + pos * 4) = val;
    }
    __syncthreads();

    // ---- phase 1: point GEMM partials; wave = one 128-wide k slice ----
    {
        int p  = tid & 63;
        int ks = tid >> 6;                 // 0..7
        float acc[TT];
        #pragma unroll
        for (int r = 0; r < TT; ++r) acc[r] = 0.f;
        int k0base = ks * 128;
        for (int kk = 0; kk < 128; kk += 4) {
            int k0 = k0base + kk;
            float w0 = Wp[(size_t)(k0 + 0) * P_ + p];
            float w1 = Wp[(size_t)(k0 + 1) * P_ + p];
            float w2 = Wp[(size_t)(k0 + 2) * P_ + p];
            float w3 = Wp[(size_t)(k0 + 3) * P_ + p];
            #pragma unroll
            for (int r = 0; r < TT; ++r) {
                float4 xv = *(const float4*)(xs + (6 + r) * FC_ + k0);
                acc[r] += xv.x * w0 + xv.y * w1 + xv.z * w2 + xv.w * w3;
            }
        }
        #pragma unroll
        for (int r = 0; r < TT; ++r)
            part[(ks * TT + r) * P_ + p] = acc[r];
    }
    __syncthreads();

    // ---- phase 1b: reduce k-slices + bias + static, ReLU into pout ----
    {
        int p = tid & 63;
        int r = tid >> 6;                  // 0..7
        float s = bp[p];
        const float* wst = Wp + (size_t)FC_ * P_;
        #pragma unroll 8
        for (int si = 0; si < S_; ++si)
            s += stat[b * S_ + si] * wst[si * P_ + p];
        #pragma unroll
        for (int ks = 0; ks < 8; ++ks)
            s += part[(ks * TT + r) * P_ + p];
        pout[r * P_ + p] = fmaxf(s, 0.f);
    }
    __syncthreads();

    // ---- phase 2: conv + fused concat/ReLU stores ----
    int p  = tid & 63;
    int fg = tid >> 6;                     // 0..7
    float pv[TT];
    #pragma unroll
    for (int r = 0; r < TT; ++r) pv[r] = pout[r * P_ + p];

    int co = tid & 15;
    int fh = tid >> 4;                     // 0..31
    #pragma unroll
    for (int half = 0; half < 2; ++half) {
        int f = fh + half * 32;
        // conv weights for (f, co): 64 floats in registers (cw read once/block)
        float w[64];
        const float4* wg = (const float4*)(cw + ((size_t)(f * CO_ + co)) * (C_ * K_));
        #pragma unroll
        for (int j = 0; j < 16; ++j) {
            float4 t4 = wg[j];
            w[4 * j + 0] = t4.x; w[4 * j + 1] = t4.y;
            w[4 * j + 2] = t4.z; w[4 * j + 3] = t4.w;
        }
        float bias = cb[f * CO_ + co];
        for (int tl = 0; tl < TT; ++tl) {
            float temp = bias;
            #pragma unroll
            for (int k = 0; k < K_; ++k) {
                const float* sp = xs + (tl + 2 * k) * FC_ + f * C_;
                #pragma unroll
                for (int c4 = 0; c4 < 4; ++c4) {
                    float4 xv = *(const float4*)(sp + c4 * 4);
                    temp += xv.x * w[(c4 * 4 + 0) * 4 + k];
                    temp += xv.y * w[(c4 * 4 + 1) * 4 + k];
                    temp += xv.z * w[(c4 * 4 + 2) * 4 + k];
                    temp += xv.w * w[(c4 * 4 + 3) * 4 + k];
                }
            }
            float* ob = out + ((size_t)(b * T_ + t0 + tl)) * F_ * OUTC;
            ob[f * OUTC + 16 + co] = fmaxf(temp, 0.f);                       // conv
            ob[f * OUTC + co] = fmaxf(xs[(tl + 6) * FC_ + f * C_ + co], 0.f); // x pass
        }
    }
    // point broadcast: coalesced 256B chunks
    for (int tl = 0; tl < TT; ++tl) {
        float* ob = out + ((size_t)(b * T_ + t0 + tl)) * F_ * OUTC + 32 + p;
        float val = pv[tl];
        #pragma unroll
        for (int fo = 0; fo < 8; ++fo)
            ob[(fo * 8 + fg) * OUTC] = val;
    }
}

extern "C" void kernel_launch(void* const* d_in, const int* in_sizes, int n_in,
                              void* d_out, int out_size, void* d_ws, size_t ws_size,
                              hipStream_t stream) {
    const float* x    = (const float*)d_in[0];
    const float* stat = (const float*)d_in[1];
    const float* cw   = (const float*)d_in[2];
    const float* cb   = (const float*)d_in[3];
    const float* Wp   = (const float*)d_in[4];
    const float* bp   = (const float*)d_in[5];
    float* out = (float*)d_out;

    tpc_fused<<<1024, 512, 0, stream>>>(x, stat, cw, cb, Wp, bp, out);
}

// Round 3
// 279.067 us; speedup vs baseline: 1.3968x; 1.3968x over previous
//
#include <hip/hip_runtime.h>

#define B_  32
#define T_  256
#define F_  64
#define C_  16
#define CO_ 16
#define P_  64
#define S_  32
#define K_  4
#define FC_ 1024   // F*C
#define OUTC 96
#define TT  8      // t-tile per block
#define NS  14     // TT + 6 halo slices (dilation*(K-1) = 6)

// Fused kernel, LDS-staged output writes.
//  block = (b, 8-wide t tile, ALL f), 512 threads, 1024 blocks.
//  LDS: xs = x[t0-6..t0+7,:,:] (57.3 KB); u = 16 KB union:
//    phase 1: u[0..4096)  = point-GEMM partials (8 k-slices x 8 rows x 64 p)
//    phase 2: u[0..3072)  = output staging (32 f x 96 ch, one t, one f-half)
//             u[3072..3584) = relu(point_out) for the 8 t-rows
//  All global stores are contiguous float4 dumps -> full 128B lines, no RFO.
__global__ __launch_bounds__(512, 4) void tpc_fused(
    const float* __restrict__ x, const float* __restrict__ stat,
    const float* __restrict__ cw, const float* __restrict__ cb,
    const float* __restrict__ Wp, const float* __restrict__ bp,
    float* __restrict__ out)
{
    __shared__ __align__(16) float xs[NS * FC_];   // 57.3 KB
    __shared__ __align__(16) float u[4096];        // 16 KB multi-use

    int tid = threadIdx.x;
    int blk = blockIdx.x;      // 0..1023
    int b  = blk >> 5;
    int t0 = (blk & 31) * TT;

    // ---- stage x[t0-6 .. t0+TT-1, :, :] into LDS (zero left pad) ----
    #pragma unroll
    for (int it = 0; it < 7; ++it) {
        int v = it * 512 + tid;            // float4 id, NS*256 = 3584 total
        int slice = v >> 8;
        int pos   = v & 255;
        int tg = t0 - 6 + slice;
        float4 val = make_float4(0.f, 0.f, 0.f, 0.f);
        if (tg >= 0)
            val = *(const float4*)(x + ((size_t)(b * T_ + tg)) * FC_ + pos * 4);
        *(float4*)(xs + slice * FC_ + pos * 4) = val;
    }
    __syncthreads();

    // ---- phase 1: point GEMM partials; wave = one 128-wide k slice ----
    {
        int p  = tid & 63;
        int ks = tid >> 6;                 // 0..7
        float acc[TT];
        #pragma unroll
        for (int r = 0; r < TT; ++r) acc[r] = 0.f;
        int k0base = ks * 128;
        for (int kk = 0; kk < 128; kk += 4) {
            int k0 = k0base + kk;
            float w0 = Wp[(size_t)(k0 + 0) * P_ + p];
            float w1 = Wp[(size_t)(k0 + 1) * P_ + p];
            float w2 = Wp[(size_t)(k0 + 2) * P_ + p];
            float w3 = Wp[(size_t)(k0 + 3) * P_ + p];
            #pragma unroll
            for (int r = 0; r < TT; ++r) {
                float4 xv = *(const float4*)(xs + (6 + r) * FC_ + k0);
                acc[r] += xv.x * w0 + xv.y * w1 + xv.z * w2 + xv.w * w3;
            }
        }
        #pragma unroll
        for (int r = 0; r < TT; ++r)
            u[(ks * TT + r) * P_ + p] = acc[r];
    }
    __syncthreads();

    // ---- phase 1b: reduce + bias + static; relu into u[3072..3584) ----
    {
        int p = tid & 63;
        int r = tid >> 6;                  // row 0..7
        float s = bp[p];
        const float* wst = Wp + (size_t)FC_ * P_;
        #pragma unroll 8
        for (int si = 0; si < S_; ++si)
            s += stat[b * S_ + si] * wst[si * P_ + p];
        #pragma unroll
        for (int ks = 0; ks < 8; ++ks)
            s += u[(ks * TT + r) * P_ + p];
        __syncthreads();                   // all part reads done before overwrite
        u[3072 + r * P_ + p] = fmaxf(s, 0.f);
    }
    __syncthreads();

    // ---- phase 2: conv + concat fusion, LDS-staged full-line dumps ----
    int co = tid & 15;
    int fh = tid >> 4;                     // 0..31 (local f within half)
    int p  = tid & 63;
    int fg = tid >> 6;                     // 0..7

    #pragma unroll
    for (int half = 0; half < 2; ++half) {
        int f = half * 32 + fh;
        // conv weights for (f, co): 64 floats (cw read once per block total)
        float w[64];
        const float4* wg = (const float4*)(cw + ((size_t)(f * CO_ + co)) * (C_ * K_));
        #pragma unroll
        for (int j = 0; j < 16; ++j) {
            float4 t4 = wg[j];
            w[4 * j + 0] = t4.x; w[4 * j + 1] = t4.y;
            w[4 * j + 2] = t4.z; w[4 * j + 3] = t4.w;
        }
        float bias = cb[f * CO_ + co];

        for (int tl = 0; tl < TT; ++tl) {
            // conv result -> staging
            float temp = bias;
            #pragma unroll
            for (int k = 0; k < K_; ++k) {
                const float* sp = xs + (tl + 2 * k) * FC_ + f * C_;
                #pragma unroll
                for (int c4 = 0; c4 < 4; ++c4) {
                    float4 xv = *(const float4*)(sp + c4 * 4);
                    temp += xv.x * w[(c4 * 4 + 0) * 4 + k];
                    temp += xv.y * w[(c4 * 4 + 1) * 4 + k];
                    temp += xv.z * w[(c4 * 4 + 2) * 4 + k];
                    temp += xv.w * w[(c4 * 4 + 3) * 4 + k];
                }
            }
            u[fh * OUTC + 16 + co] = fmaxf(temp, 0.f);
            // x passthrough -> staging
            u[fh * OUTC + co] = fmaxf(xs[(tl + 6) * FC_ + f * C_ + co], 0.f);
            // point broadcast -> staging (reads u[3072..), writes u[0..3072): disjoint)
            float pvv = u[3072 + tl * P_ + p];
            #pragma unroll
            for (int fo = 0; fo < 4; ++fo)
                u[(fo * 8 + fg) * OUTC + 32 + p] = pvv;
            __syncthreads();
            // dump 12 KB contiguous (full 128B lines, perfectly coalesced)
            {
                const float4* src = (const float4*)u;
                float4* dst = (float4*)(out + ((size_t)(b * T_ + t0 + tl)) * F_ * OUTC
                                        + half * 3072);
                dst[tid] = src[tid];
                if (tid < 256) dst[512 + tid] = src[512 + tid];
            }
            __syncthreads();
        }
    }
}

extern "C" void kernel_launch(void* const* d_in, const int* in_sizes, int n_in,
                              void* d_out, int out_size, void* d_ws, size_t ws_size,
                              hipStream_t stream) {
    const float* x    = (const float*)d_in[0];
    const float* stat = (const float*)d_in[1];
    const float* cw   = (const float*)d_in[2];
    const float* cb   = (const float*)d_in[3];
    const float* Wp   = (const float*)d_in[4];
    const float* bp   = (const float*)d_in[5];
    float* out = (float*)d_out;

    tpc_fused<<<1024, 512, 0, stream>>>(x, stat, cw, cb, Wp, bp, out);
}